// Round 18
// baseline (93.388 us; speedup 1.0000x reference)
//
#include <hip/hip_runtime.h>
#include <hip/hip_bf16.h>
#include <math.h>

typedef unsigned short u16;
typedef unsigned int u32;
typedef __attribute__((ext_vector_type(8))) __bf16 bf16x8;
typedef __attribute__((ext_vector_type(4))) float f32x4;

__device__ inline u16 f2bf(float f) {
  u32 b = __float_as_uint(f);
  b += 0x7FFFu + ((b >> 16) & 1u);
  return (u16)(b >> 16);
}
__device__ inline float bf2f(u16 b) { return __uint_as_float((u32)b << 16); }

// async global->LDS, 16 bytes per lane; LDS dest = uniform base + lane*16
__device__ __forceinline__ void gll16(const void* gp, void* lp) {
  __builtin_amdgcn_global_load_lds(
      (const __attribute__((address_space(1))) void*)gp,
      (__attribute__((address_space(3))) void*)lp, 16, 0, 0);
}

// ---------------- fused prep: cvt | weight transposes | rope table ----------
// grid 4224 x 256: [0,1024) cvt x->xb ; [1024,3968) prep_w ; [3968,4224) rope
__global__ __launch_bounds__(256) void prep_all_k(
    const float* __restrict__ x, const int* __restrict__ positions,
    const float* __restrict__ Wq, const float* __restrict__ Wk,
    const float* __restrict__ Wv, const float* __restrict__ Wvr,
    const float* __restrict__ Wo, const float* __restrict__ Wg,
    const float* __restrict__ Wm, u16* __restrict__ xb,
    u16* __restrict__ WallT, u16* __restrict__ WoT, float* __restrict__ rtab) {
  __shared__ float tile[32][33];
  int bid = blockIdx.x, tid = threadIdx.x;
  if (bid < 1024) {  // ---- cvt ----
    int i = (bid * 256 + tid) * 8;
    float4 v0 = *(const float4*)&x[i];
    float4 v1 = *(const float4*)&x[i + 4];
    uint4 pk;
    pk.x = (u32)f2bf(v0.x) | ((u32)f2bf(v0.y) << 16);
    pk.y = (u32)f2bf(v0.z) | ((u32)f2bf(v0.w) << 16);
    pk.z = (u32)f2bf(v1.x) | ((u32)f2bf(v1.y) << 16);
    pk.w = (u32)f2bf(v1.z) | ((u32)f2bf(v1.w) << 16);
    *(uint4*)&xb[i] = pk;
    return;
  }
  if (bid >= 3968) {  // ---- rope table ----
    int idx = (bid - 3968) * 256 + tid;
    int s = idx >> 5, f = idx & 31;
    float inv = __expf(-(float)f * (9.210340371976184f / 32.f));
    float ang = (float)positions[s] * inv;
    rtab[(size_t)s * 64 + f] = cosf(ang);
    rtab[(size_t)s * 64 + 32 + f] = sinf(ang);
    return;
  }
  // ---- weight prep ----
  int b2 = bid - 1024;
  int k0 = (b2 & 31) * 32;
  int ybl = b2 >> 5;
  int tx = tid & 31, ty = tid >> 5;
  const float* src;
  int scol, sN, drow;
  u16* dst;
  if (ybl >= 60) {
    src = Wo; scol = (ybl - 60) * 32; sN = 1024; dst = WoT; drow = scol;
  } else {
    int n0 = ybl * 32;
    if (n0 >= 1792) {  // Wg/Wm/zero region, direct (no LDS)
#pragma unroll
      for (int j = 0; j < 4; ++j) {
        int n = n0 + ty * 4 + j, j2 = n - 1792, k = k0 + tx;
        float val = (j2 < 16) ? Wg[(size_t)k * 16 + j2]
                  : (j2 < 20) ? Wm[(size_t)k * 4 + (j2 - 16)] : 0.f;
        WallT[(size_t)n * 1024 + k] = f2bf(val);
      }
      return;
    }
    dst = WallT; drow = n0;
    if (n0 < 1024) { src = Wq; scol = n0; sN = 1024; }
    else if (n0 < 1280) { src = Wk; scol = n0 - 1024; sN = 256; }
    else if (n0 < 1536) { src = Wv; scol = n0 - 1280; sN = 256; }
    else { src = Wvr; scol = n0 - 1536; sN = 256; }
  }
#pragma unroll
  for (int j = 0; j < 4; ++j)
    tile[ty * 4 + j][tx] = src[(size_t)(k0 + ty * 4 + j) * sN + scol + tx];
  __syncthreads();
#pragma unroll
  for (int j = 0; j < 4; ++j)
    dst[(size_t)(drow + ty * 4 + j) * 1024 + k0 + tx] = f2bf(tile[tx][ty * 4 + j]);
}

// ---------------- bf16 MFMA GEMM: C[M,N] = A[M,K] @ Bt[N,K]^T ---------------
// staging via global_load_lds width=16 (m97 pattern): linear LDS, per-lane
// global src; lane l of wave-segment covers row seg*8+l/8, cols (l&7)*8.
template <int BM, bool BF16_OUT>
__global__ __launch_bounds__(512) void gemm_bf16_k(
    const u16* __restrict__ A, const u16* __restrict__ Bt, void* __restrict__ Cv,
    int M, int N, int K) {
  constexpr int MI = BM / 32;
  __shared__ __align__(16) u16 As[BM * 64];
  __shared__ __align__(16) u16 Bs[128 * 64];
  int tid = threadIdx.x;
  int w = tid >> 6, l = tid & 63;
  int wr = w >> 2, wc = w & 3;
  int lr = l & 15, lg = l >> 4;
  int lrow = l >> 3, lcol = (l & 7) * 8;  // staging decomposition
  int m0 = blockIdx.y * BM, n0 = blockIdx.x * 128;
  f32x4 zero = {0.f, 0.f, 0.f, 0.f};
  f32x4 acc[MI][2];
#pragma unroll
  for (int mi = 0; mi < MI; ++mi)
#pragma unroll
    for (int ni = 0; ni < 2; ++ni) acc[mi][ni] = zero;

  for (int kt = 0; kt < K; kt += 64) {
    __syncthreads();  // previous tile's reads done before overwrite
#pragma unroll
    for (int t = 0; t < BM / 64; ++t) {
      int seg = t * 8 + w;
      gll16(&A[(size_t)(m0 + seg * 8 + lrow) * K + kt + lcol], &As[seg * 512]);
    }
#pragma unroll
    for (int t = 0; t < 2; ++t) {
      int seg = t * 8 + w;
      gll16(&Bt[(size_t)(n0 + seg * 8 + lrow) * K + kt + lcol], &Bs[seg * 512]);
    }
    __syncthreads();  // compiler drains vmcnt before this barrier
#pragma unroll
    for (int kw = 0; kw < 2; ++kw) {
      bf16x8 af[MI], bfr[2];
#pragma unroll
      for (int mi = 0; mi < MI; ++mi)
        af[mi] = *(const bf16x8*)&As[(wr * (BM / 2) + mi * 16 + lr) * 64 + kw * 32 + lg * 8];
#pragma unroll
      for (int ni = 0; ni < 2; ++ni)
        bfr[ni] = *(const bf16x8*)&Bs[(wc * 32 + ni * 16 + lr) * 64 + kw * 32 + lg * 8];
#pragma unroll
      for (int mi = 0; mi < MI; ++mi)
#pragma unroll
        for (int ni = 0; ni < 2; ++ni)
          acc[mi][ni] = __builtin_amdgcn_mfma_f32_16x16x32_bf16(
              af[mi], bfr[ni], acc[mi][ni], 0, 0, 0);
    }
  }
#pragma unroll
  for (int mi = 0; mi < MI; ++mi)
#pragma unroll
    for (int ni = 0; ni < 2; ++ni)
#pragma unroll
      for (int r = 0; r < 4; ++r) {
        int row = m0 + wr * (BM / 2) + mi * 16 + lg * 4 + r;
        int col = n0 + wc * 32 + ni * 16 + lr;
        if (BF16_OUT)
          ((u16*)Cv)[(size_t)row * N + col] = f2bf(acc[mi][ni][r]);
        else
          ((float*)Cv)[(size_t)row * N + col] = acc[mi][ni][r];
      }
}

// ---------------- postprocess (no LDS, no barriers) -------------------------
__global__ __launch_bounds__(256) void postproc_k(
    const float* __restrict__ bm, const float* __restrict__ ksc,
    const float* __restrict__ rtab, u16* __restrict__ qkvrb,
    u16* __restrict__ kb, u16* __restrict__ vb, float* __restrict__ g_out) {
  int s = blockIdx.x, tid = threadIdx.x;
  int lane = tid & 63, w = tid >> 6;
  u16* row = qkvrb + (size_t)s * 1920;
  const float* tr = rtab + (size_t)s * 64;
  if (tid < 16)
    g_out[s * 16 + tid] = 1.f / (1.f + __expf(-bf2f(row[1792 + tid])));
  int h = w, d = lane;
  float c = tr[d >> 1], sn = tr[32 + (d >> 1)];
  {  // v mix -> vb [h][s][d]
    float mixv = 1.f / (1.f + __expf(-(bf2f(row[1808 + h]) + bm[h])));
    float vv = bf2f(row[1280 + h * 64 + d]);
    float rv = bf2f(row[1536 + h * 64 + d]);
    vb[((size_t)h * 2048 + s) * 64 + d] = f2bf(vv + mixv * (rv - vv));
  }
  {  // k: RMSNorm * k_scale + RoPE -> kb [h][s][d]
    float kv = bf2f(row[1024 + h * 64 + d]);
    float ss = kv * kv;
#pragma unroll
    for (int off = 32; off > 0; off >>= 1) ss += __shfl_xor(ss, off);
    float rms = sqrtf(ss * (1.f / 64.f) + 1e-8f);
    float kn = kv / rms * ksc[h * 64 + d];
    float partner = __shfl_xor(kn, 1);
    kb[((size_t)h * 2048 + s) * 64 + d] =
        f2bf((d & 1) ? fmaf(kn, c, partner * sn) : fmaf(kn, c, -partner * sn));
  }
#pragma unroll
  for (int r = 0; r < 4; ++r) {  // q RoPE in-place, pre-scaled by 0.125
    int e = r * 256 + tid;
    int dq = e & 63;
    float cq = tr[dq >> 1], sq = tr[32 + (dq >> 1)];
    float qv = bf2f(row[e]);
    float partner = __shfl_xor(qv, 1);
    float qr = (e & 1) ? fmaf(qv, cq, partner * sq) : fmaf(qv, cq, -partner * sq);
    row[e] = f2bf(qr * 0.125f);
  }
}

// ---------------- vb [h][s][d] -> vtb [h][d][s] -----------------------------
#define TPAD 66
__global__ __launch_bounds__(256) void vtrans_k(const u16* __restrict__ vb,
                                               u16* __restrict__ vtb) {
  __shared__ u16 tile[64 * TPAD];
  int h = blockIdx.y, s0 = blockIdx.x * 64;
  int t = threadIdx.x;
  {
    int r = t >> 2, cb = (t & 3) * 16;
    const u16* src = vb + ((size_t)h * 2048 + s0 + r) * 64 + cb;
    *(uint4*)&tile[r * TPAD + cb] = *(const uint4*)src;
    *(uint4*)&tile[r * TPAD + cb + 8] = *(const uint4*)(src + 8);
  }
  __syncthreads();
  int d = t >> 2, sb = (t & 3) * 16;
  u16 vals[16];
#pragma unroll
  for (int j = 0; j < 16; ++j) vals[j] = tile[(sb + j) * TPAD + d];
  uint4 a, b;
  a.x = (u32)vals[0] | ((u32)vals[1] << 16);
  a.y = (u32)vals[2] | ((u32)vals[3] << 16);
  a.z = (u32)vals[4] | ((u32)vals[5] << 16);
  a.w = (u32)vals[6] | ((u32)vals[7] << 16);
  b.x = (u32)vals[8] | ((u32)vals[9] << 16);
  b.y = (u32)vals[10] | ((u32)vals[11] << 16);
  b.z = (u32)vals[12] | ((u32)vals[13] << 16);
  b.w = (u32)vals[14] | ((u32)vals[15] << 16);
  u16* dst = vtb + ((size_t)h * 64 + d) * 2048 + s0 + sb;
  *(uint4*)dst = a;
  *(uint4*)(dst + 8) = b;
}

// ---------------- MFMA causal attention, FUSED-PAIR single pass -------------
// grid (16 heads, 16), 512 thr = 2 parity groups x 4 waves. Block owns row
// blocks rbH=31-by and rbL=by; light's chunks [0..rbL] are a SUBSET of
// heavy's [0..rbH], so ONE pass over chunks 0..rbH computes both (two acc
// sets), staging each chunk once. gll16 staging, XOR-swizzled K/V, LDS-P
// redistribution (wave-private, in-order), fixed-50 softmax, one merge.
__global__ __launch_bounds__(512, 2) void attn_k(
    const u16* __restrict__ qkvrb, const u16* __restrict__ kb,
    const u16* __restrict__ vtb, const float* __restrict__ g,
    u16* __restrict__ aob) {
  __shared__ __align__(16) u16 smem[40960];  // 80KB: 64KB K/V dbuf + 16KB Pw
  int head = blockIdx.x, hkv = head >> 2;
  int by = blockIdx.y;
  int rbH = 31 - by, rbL = by;
  int row0H = rbH * 64, row0L = rbL * 64;
  int tid = threadIdx.x;
  int w = tid >> 6, l = tid & 63;
  int grp = w >> 2, wi = w & 3;
  int lr = l & 15, lg = l >> 4;
  int gtid = wi * 64 + l;
  u16* KsBase = smem + grp * 16384;  // buf b: Ks = +b*8192, Vt = Ks + 4096
  u32* pw = (u32*)(smem + 32768) + (size_t)w * 512;  // per-wave 16 x 32 u32
  float* mbuf = (float*)smem;        // merge: 256 x 34 f32 (34.8 KB, aliases)
  f32x4 zero = {0.f, 0.f, 0.f, 0.f};
  const float C1 = 0.057707801635558534f;  // 0.04 * log2(e)
  const float C2 = -144.26950408889634f;   // -100 * log2(e)
  int sw = (lr & 7) << 2;                  // P-tile column swizzle
  int u0 = ((lg ^ (lr & 7)) << 3);         // K/V physical u16 offset of unit
  int srow = l >> 3;
  int sunit = (l & 7) ^ srow;
  const u16* ksrc = kb + ((size_t)hkv * 2048 + srow) * 64 + sunit * 8;
  const u16* vsrc = vtb + ((size_t)(hkv * 64 + srow)) * 2048 + sunit * 8;
  // q fragments for both halves (B-frag: col=q=lr, k=lg*8), pre-scaled
  const u16* qrowH = qkvrb + (size_t)(row0H + wi * 16 + lr) * 1920 + head * 64;
  const u16* qrowL = qkvrb + (size_t)(row0L + wi * 16 + lr) * 1920 + head * 64;
  bf16x8 qfH0 = *(const bf16x8*)&qrowH[lg * 8];
  bf16x8 qfH1 = *(const bf16x8*)&qrowH[32 + lg * 8];
  bf16x8 qfL0 = *(const bf16x8*)&qrowL[lg * 8];
  bf16x8 qfL1 = *(const bf16x8*)&qrowL[32 + lg * 8];
  f32x4 accH[4], accL[4];
#pragma unroll
  for (int nd = 0; nd < 4; ++nd) {
    accH[nd] = zero;
    accL[nd] = zero;
  }
  float lH = 0.f, lL = 0.f;
  int qglobH = row0H + wi * 16 + lr;
  int qglobL = row0L + wi * 16 + lr;
  int c = grp;
  {  // prologue: stage chunk grp into buf0 (async); rbH >= 16 > grp always
#pragma unroll
    for (int t = 0; t < 2; ++t) {
      int seg = wi * 2 + t;
      gll16(ksrc + (size_t)(c * 64 + seg * 8) * 64, KsBase + seg * 512);
      gll16(vsrc + (size_t)(seg * 8) * 2048 + c * 64, KsBase + 4096 + seg * 512);
    }
  }
  __syncthreads();  // drains vmcnt: buf0 ready
  int nmax = (rbH >> 1) + 1;
#pragma unroll 1
  for (int i = 0; i < nmax; ++i, c += 2) {
    bool valid = (c <= rbH);
    if (c + 2 <= rbH) {  // async-stage chunk c+2 into other buf (overlaps)
      u16* Ksn = KsBase + ((i & 1) ^ 1) * 8192;
      int nc = c + 2;
#pragma unroll
      for (int t = 0; t < 2; ++t) {
        int seg = wi * 2 + t;
        gll16(ksrc + (size_t)(nc * 64 + seg * 8) * 64, Ksn + seg * 512);
        gll16(vsrc + (size_t)(seg * 8) * 2048 + nc * 64, Ksn + 4096 + seg * 512);
      }
    }
    if (valid) {
      u16* Ks = KsBase + (i & 1) * 8192;
      u16* Vt = Ks + 4096;
      int kbase = c * 64;
      __builtin_amdgcn_s_setprio(1);
      // ---------- heavy half ----------
      {
        f32x4 sa[4];
#pragma unroll
        for (int ni = 0; ni < 4; ++ni) {
          const u16* kp = &Ks[(ni * 16 + lr) * 64];
          bf16x8 a0 = *(const bf16x8*)&kp[u0];
          bf16x8 a1 = *(const bf16x8*)&kp[u0 ^ 32];
          f32x4 t = __builtin_amdgcn_mfma_f32_16x16x32_bf16(a0, qfH0, zero, 0, 0, 0);
          sa[ni] = __builtin_amdgcn_mfma_f32_16x16x32_bf16(a1, qfH1, t, 0, 0, 0);
        }
        bool diag = (c == rbH);
#pragma unroll
        for (int ni = 0; ni < 4; ++ni) {
          float pv[4];
#pragma unroll
          for (int r = 0; r < 4; ++r) {
            float sv = sa[ni][r];
            float e = __builtin_amdgcn_exp2f(sv * C1);
            float p = __builtin_amdgcn_exp2f(C2 * __builtin_amdgcn_rcpf(e + 1.f));
            if (diag && (kbase + ni * 16 + lg * 4 + r) > qglobH) p = 0.f;
            pv[r] = p;
            lH += p;
          }
          u32 w0, w1;
          asm("v_cvt_pk_bf16_f32 %0, %1, %2" : "=v"(w0) : "v"(pv[0]), "v"(pv[1]));
          asm("v_cvt_pk_bf16_f32 %0, %1, %2" : "=v"(w1) : "v"(pv[2]), "v"(pv[3]));
          uint2 pr;
          pr.x = w0;
          pr.y = w1;
          *(uint2*)&pw[lr * 32 + ((ni * 8 + lg * 2) ^ sw)] = pr;
        }
        bf16x8 pfa = *(const bf16x8*)&pw[lr * 32 + ((lg * 4) ^ sw)];
        bf16x8 pfb = *(const bf16x8*)&pw[lr * 32 + ((16 + lg * 4) ^ sw)];
#pragma unroll
        for (int nd = 0; nd < 4; ++nd) {
          const u16* vp = &Vt[(nd * 16 + lr) * 64];
          bf16x8 v0 = *(const bf16x8*)&vp[u0];
          bf16x8 v1 = *(const bf16x8*)&vp[u0 ^ 32];
          accH[nd] = __builtin_amdgcn_mfma_f32_16x16x32_bf16(pfa, v0, accH[nd], 0, 0, 0);
          accH[nd] = __builtin_amdgcn_mfma_f32_16x16x32_bf16(pfb, v1, accH[nd], 0, 0, 0);
        }
      }
      // ---------- light half (chunks subset; reuses staged K/V and Pw) -----
      if (c <= rbL) {
        f32x4 sa[4];
#pragma unroll
        for (int ni = 0; ni < 4; ++ni) {
          const u16* kp = &Ks[(ni * 16 + lr) * 64];
          bf16x8 a0 = *(const bf16x8*)&kp[u0];
          bf16x8 a1 = *(const bf16x8*)&kp[u0 ^ 32];
          f32x4 t = __builtin_amdgcn_mfma_f32_16x16x32_bf16(a0, qfL0, zero, 0, 0, 0);
          sa[ni] = __builtin_amdgcn_mfma_f32_16x16x32_bf16(a1, qfL1, t, 0, 0, 0);
        }
        bool diag = (c == rbL);
#pragma unroll
        for (int ni = 0; ni < 4; ++ni) {
          float pv[4];
#pragma unroll
          for (int r = 0; r < 4; ++r) {
            float sv = sa[ni][r];
            float e = __builtin_amdgcn_exp2f(sv * C1);
            float p = __builtin_amdgcn_exp2f(C2 * __builtin_amdgcn_rcpf(e + 1.f));
            if (diag && (kbase + ni * 16 + lg * 4 + r) > qglobL) p = 0.f;
            pv[r] = p;
            lL += p;
          }
          u32 w0, w1;
          asm("v_cvt_pk_bf16_f32 %0, %1, %2" : "=v"(w0) : "v"(pv[0]), "v"(pv[1]));
          asm("v_cvt_pk_bf16_f32 %0, %1, %2" : "=v"(w1) : "v"(pv[2]), "v"(pv[3]));
          uint2 pr;
          pr.x = w0;
          pr.y = w1;
          *(uint2*)&pw[lr * 32 + ((ni * 8 + lg * 2) ^ sw)] = pr;
        }
        bf16x8 pfa = *(const bf16x8*)&pw[lr * 32 + ((lg * 4) ^ sw)];
        bf16x8 pfb = *(const bf16x8*)&pw[lr * 32 + ((16 + lg * 4) ^ sw)];
#pragma unroll
        for (int nd = 0; nd < 4; ++nd) {
          const u16* vp = &Vt[(nd * 16 + lr) * 64];
          bf16x8 v0 = *(const bf16x8*)&vp[u0];
          bf16x8 v1 = *(const bf16x8*)&vp[u0 ^ 32];
          accL[nd] = __builtin_amdgcn_mfma_f32_16x16x32_bf16(pfa, v0, accL[nd], 0, 0, 0);
          accL[nd] = __builtin_amdgcn_mfma_f32_16x16x32_bf16(pfb, v1, accL[nd], 0, 0, 0);
        }
      }
      __builtin_amdgcn_s_setprio(0);
    }
    __syncthreads();  // the only barrier per chunk (drains vmcnt+lgkm)
  }
  // reduce l within wave (sum 4 lg copies of each q-row)
  lH += __shfl_xor(lH, 16);
  lH += __shfl_xor(lH, 32);
  lL += __shfl_xor(lL, 16);
  lL += __shfl_xor(lL, 32);
  // merge parity groups via LDS (K/V buffers dead)
  if (grp == 1) {
    float* mb = mbuf + (size_t)gtid * 34;
#pragma unroll
    for (int nd = 0; nd < 4; ++nd)
#pragma unroll
      for (int r = 0; r < 4; ++r) {
        mb[nd * 4 + r] = accH[nd][r];
        mb[16 + nd * 4 + r] = accL[nd][r];
      }
    mb[32] = lH;
    mb[33] = lL;
  }
  __syncthreads();
  if (grp == 0) {
    const float* mb = mbuf + (size_t)gtid * 34;
    float ltH = lH + mb[32];
    float ltL = lL + mb[33];
#pragma unroll
    for (int r = 0; r < 4; ++r) {
      int rowH = row0H + wi * 16 + lg * 4 + r;
      int rowL = row0L + wi * 16 + lg * 4 + r;
      float lvH = __shfl(ltH, lg * 4 + r);
      float lvL = __shfl(ltL, lg * 4 + r);
      float scH = g[rowH * 16 + head] * __builtin_amdgcn_rcpf(lvH);
      float scL = g[rowL * 16 + head] * __builtin_amdgcn_rcpf(lvL);
#pragma unroll
      for (int nd = 0; nd < 4; ++nd) {
        aob[(size_t)rowH * 1024 + head * 64 + nd * 16 + lr] =
            f2bf((accH[nd][r] + mb[nd * 4 + r]) * scH);
        aob[(size_t)rowL * 1024 + head * 64 + nd * 16 + lr] =
            f2bf((accL[nd][r] + mb[16 + nd * 4 + r]) * scL);
      }
    }
  }
}

extern "C" void kernel_launch(void* const* d_in, const int* in_sizes, int n_in,
                              void* d_out, int out_size, void* d_ws,
                              size_t ws_size, hipStream_t stream) {
  const float* x = (const float*)d_in[0];
  const int* positions = (const int*)d_in[1];
  const float* Wq = (const float*)d_in[3];
  const float* Wk = (const float*)d_in[4];
  const float* Wv = (const float*)d_in[5];
  const float* Wo = (const float*)d_in[6];
  const float* Wg = (const float*)d_in[7];
  const float* Wm = (const float*)d_in[8];
  const float* bm = (const float*)d_in[9];
  const float* Wvr = (const float*)d_in[10];
  const float* ksc = (const float*)d_in[11];
  float* out = (float*)d_out;

  u16* xb = (u16*)d_ws;                            // 2048*1024
  u16* WallT = xb + (size_t)2048 * 1024;           // 1920*1024
  u16* WoT = WallT + (size_t)1920 * 1024;          // 1024*1024
  u16* qkvrb = WoT + (size_t)1024 * 1024;          // 2048*1920
  u16* kbuf = qkvrb + (size_t)2048 * 1920;         // 4*2048*64
  u16* vbuf = kbuf + (size_t)4 * 2048 * 64;
  u16* vtb = vbuf + (size_t)4 * 2048 * 64;
  float* gbuf = (float*)(vtb + (size_t)4 * 2048 * 64);  // 2048*16 f32
  float* rtab = gbuf + (size_t)2048 * 16;               // 2048*64 f32
  u16* aob = xb;  // xb dead after gemm1

  prep_all_k<<<4224, 256, 0, stream>>>(x, positions, Wq, Wk, Wv, Wvr, Wo, Wg,
                                       Wm, xb, WallT, WoT, rtab);
  gemm_bf16_k<128, true><<<dim3(15, 16), 512, 0, stream>>>(xb, WallT, qkvrb,
                                                           2048, 1920, 1024);
  postproc_k<<<2048, 256, 0, stream>>>(bm, ksc, rtab, qkvrb, kbuf, vbuf, gbuf);
  vtrans_k<<<dim3(32, 4), 256, 0, stream>>>(vbuf, vtb);
  attn_k<<<dim3(16, 16), 512, 0, stream>>>(qkvrb, kbuf, vtb, gbuf, aob);
  gemm_bf16_k<64, false><<<dim3(8, 32), 512, 0, stream>>>(aob, WoT, out, 2048,
                                                          1024, 1024);
}

// Round 20
// 88.056 us; speedup vs baseline: 1.0606x; 1.0606x over previous
//
#include <hip/hip_runtime.h>
#include <hip/hip_bf16.h>
#include <math.h>

typedef unsigned short u16;
typedef unsigned int u32;
typedef __attribute__((ext_vector_type(8))) __bf16 bf16x8;
typedef __attribute__((ext_vector_type(4))) float f32x4;

__device__ inline u16 f2bf(float f) {
  u32 b = __float_as_uint(f);
  b += 0x7FFFu + ((b >> 16) & 1u);
  return (u16)(b >> 16);
}
__device__ inline float bf2f(u16 b) { return __uint_as_float((u32)b << 16); }

// async global->LDS, 16 bytes per lane; LDS dest = uniform base + lane*16
__device__ __forceinline__ void gll16(const void* gp, void* lp) {
  __builtin_amdgcn_global_load_lds(
      (const __attribute__((address_space(1))) void*)gp,
      (__attribute__((address_space(3))) void*)lp, 16, 0, 0);
}

// ---------------- fused prep: cvt | weight transposes | rope table ----------
// grid 4224 x 256: [0,1024) cvt x->xb ; [1024,3968) prep_w ; [3968,4224) rope
__global__ __launch_bounds__(256) void prep_all_k(
    const float* __restrict__ x, const int* __restrict__ positions,
    const float* __restrict__ Wq, const float* __restrict__ Wk,
    const float* __restrict__ Wv, const float* __restrict__ Wvr,
    const float* __restrict__ Wo, const float* __restrict__ Wg,
    const float* __restrict__ Wm, u16* __restrict__ xb,
    u16* __restrict__ WallT, u16* __restrict__ WoT, float* __restrict__ rtab) {
  __shared__ float tile[32][33];
  int bid = blockIdx.x, tid = threadIdx.x;
  if (bid < 1024) {  // ---- cvt ----
    int i = (bid * 256 + tid) * 8;
    float4 v0 = *(const float4*)&x[i];
    float4 v1 = *(const float4*)&x[i + 4];
    uint4 pk;
    pk.x = (u32)f2bf(v0.x) | ((u32)f2bf(v0.y) << 16);
    pk.y = (u32)f2bf(v0.z) | ((u32)f2bf(v0.w) << 16);
    pk.z = (u32)f2bf(v1.x) | ((u32)f2bf(v1.y) << 16);
    pk.w = (u32)f2bf(v1.z) | ((u32)f2bf(v1.w) << 16);
    *(uint4*)&xb[i] = pk;
    return;
  }
  if (bid >= 3968) {  // ---- rope table ----
    int idx = (bid - 3968) * 256 + tid;
    int s = idx >> 5, f = idx & 31;
    float inv = __expf(-(float)f * (9.210340371976184f / 32.f));
    float ang = (float)positions[s] * inv;
    rtab[(size_t)s * 64 + f] = cosf(ang);
    rtab[(size_t)s * 64 + 32 + f] = sinf(ang);
    return;
  }
  // ---- weight prep ----
  int b2 = bid - 1024;
  int k0 = (b2 & 31) * 32;
  int ybl = b2 >> 5;
  int tx = tid & 31, ty = tid >> 5;
  const float* src;
  int scol, sN, drow;
  u16* dst;
  if (ybl >= 60) {
    src = Wo; scol = (ybl - 60) * 32; sN = 1024; dst = WoT; drow = scol;
  } else {
    int n0 = ybl * 32;
    if (n0 >= 1792) {  // Wg/Wm/zero region, direct (no LDS)
#pragma unroll
      for (int j = 0; j < 4; ++j) {
        int n = n0 + ty * 4 + j, j2 = n - 1792, k = k0 + tx;
        float val = (j2 < 16) ? Wg[(size_t)k * 16 + j2]
                  : (j2 < 20) ? Wm[(size_t)k * 4 + (j2 - 16)] : 0.f;
        WallT[(size_t)n * 1024 + k] = f2bf(val);
      }
      return;
    }
    dst = WallT; drow = n0;
    if (n0 < 1024) { src = Wq; scol = n0; sN = 1024; }
    else if (n0 < 1280) { src = Wk; scol = n0 - 1024; sN = 256; }
    else if (n0 < 1536) { src = Wv; scol = n0 - 1280; sN = 256; }
    else { src = Wvr; scol = n0 - 1536; sN = 256; }
  }
#pragma unroll
  for (int j = 0; j < 4; ++j)
    tile[ty * 4 + j][tx] = src[(size_t)(k0 + ty * 4 + j) * sN + scol + tx];
  __syncthreads();
#pragma unroll
  for (int j = 0; j < 4; ++j)
    dst[(size_t)(drow + ty * 4 + j) * 1024 + k0 + tx] = f2bf(tile[tx][ty * 4 + j]);
}

// ---------------- bf16 MFMA GEMM, LDS double-buffered (T3 min-2-phase) ------
// Per K-tile: issue gll16 for tile t+1 into buf^1 FIRST, compute tile t from
// buf, then ONE barrier. Staging via a LAMBDA (round 19's macro had its KT
// argument captured by the macro-internal loop variable -> wrong K-tiles).
template <int BM, bool BF16_OUT>
__global__ __launch_bounds__(512) void gemm_bf16_k(
    const u16* __restrict__ A, const u16* __restrict__ Bt, void* __restrict__ Cv,
    int M, int N, int K) {
  constexpr int MI = BM / 32;
  __shared__ __align__(16) u16 As[2][BM * 64];
  __shared__ __align__(16) u16 Bs[2][128 * 64];
  int tid = threadIdx.x;
  int w = tid >> 6, l = tid & 63;
  int wr = w >> 2, wc = w & 3;
  int lr = l & 15, lg = l >> 4;
  int lrow = l >> 3, lcol = (l & 7) * 8;  // staging decomposition
  int m0 = blockIdx.y * BM, n0 = blockIdx.x * 128;
  f32x4 zero = {0.f, 0.f, 0.f, 0.f};
  f32x4 acc[MI][2];
#pragma unroll
  for (int mi = 0; mi < MI; ++mi)
#pragma unroll
    for (int ni = 0; ni < 2; ++ni) acc[mi][ni] = zero;

  auto gstage = [&](int buf, int kt) {
#pragma unroll
    for (int ts = 0; ts < BM / 64; ++ts) {
      int seg = ts * 8 + w;
      gll16(&A[(size_t)(m0 + seg * 8 + lrow) * K + kt + lcol],
            &As[buf][seg * 512]);
    }
#pragma unroll
    for (int ts = 0; ts < 2; ++ts) {
      int seg = ts * 8 + w;
      gll16(&Bt[(size_t)(n0 + seg * 8 + lrow) * K + kt + lcol],
            &Bs[buf][seg * 512]);
    }
  };

  gstage(0, 0);
  __syncthreads();
  int nt = K >> 6;
#pragma unroll 1
  for (int t = 0; t < nt; ++t) {
    int cur = t & 1;
    if (t + 1 < nt) gstage(cur ^ 1, (t + 1) * 64);
#pragma unroll
    for (int kw = 0; kw < 2; ++kw) {
      bf16x8 af[MI], bfr[2];
#pragma unroll
      for (int mi = 0; mi < MI; ++mi)
        af[mi] = *(const bf16x8*)&As[cur][(wr * (BM / 2) + mi * 16 + lr) * 64 + kw * 32 + lg * 8];
#pragma unroll
      for (int ni = 0; ni < 2; ++ni)
        bfr[ni] = *(const bf16x8*)&Bs[cur][(wc * 32 + ni * 16 + lr) * 64 + kw * 32 + lg * 8];
#pragma unroll
      for (int mi = 0; mi < MI; ++mi)
#pragma unroll
        for (int ni = 0; ni < 2; ++ni)
          acc[mi][ni] = __builtin_amdgcn_mfma_f32_16x16x32_bf16(
              af[mi], bfr[ni], acc[mi][ni], 0, 0, 0);
    }
    __syncthreads();  // single barrier: readers done + next-buf loads drained
  }
#pragma unroll
  for (int mi = 0; mi < MI; ++mi)
#pragma unroll
    for (int ni = 0; ni < 2; ++ni)
#pragma unroll
      for (int r = 0; r < 4; ++r) {
        int row = m0 + wr * (BM / 2) + mi * 16 + lg * 4 + r;
        int col = n0 + wc * 32 + ni * 16 + lr;
        if (BF16_OUT)
          ((u16*)Cv)[(size_t)row * N + col] = f2bf(acc[mi][ni][r]);
        else
          ((float*)Cv)[(size_t)row * N + col] = acc[mi][ni][r];
      }
}

// ---------------- postprocess (no LDS, no barriers) -------------------------
__global__ __launch_bounds__(256) void postproc_k(
    const float* __restrict__ bm, const float* __restrict__ ksc,
    const float* __restrict__ rtab, u16* __restrict__ qkvrb,
    u16* __restrict__ kb, u16* __restrict__ vb, float* __restrict__ g_out) {
  int s = blockIdx.x, tid = threadIdx.x;
  int lane = tid & 63, w = tid >> 6;
  u16* row = qkvrb + (size_t)s * 1920;
  const float* tr = rtab + (size_t)s * 64;
  if (tid < 16)
    g_out[s * 16 + tid] = 1.f / (1.f + __expf(-bf2f(row[1792 + tid])));
  int h = w, d = lane;
  float c = tr[d >> 1], sn = tr[32 + (d >> 1)];
  {  // v mix -> vb [h][s][d]
    float mixv = 1.f / (1.f + __expf(-(bf2f(row[1808 + h]) + bm[h])));
    float vv = bf2f(row[1280 + h * 64 + d]);
    float rv = bf2f(row[1536 + h * 64 + d]);
    vb[((size_t)h * 2048 + s) * 64 + d] = f2bf(vv + mixv * (rv - vv));
  }
  {  // k: RMSNorm * k_scale + RoPE -> kb [h][s][d]
    float kv = bf2f(row[1024 + h * 64 + d]);
    float ss = kv * kv;
#pragma unroll
    for (int off = 32; off > 0; off >>= 1) ss += __shfl_xor(ss, off);
    float rms = sqrtf(ss * (1.f / 64.f) + 1e-8f);
    float kn = kv / rms * ksc[h * 64 + d];
    float partner = __shfl_xor(kn, 1);
    kb[((size_t)h * 2048 + s) * 64 + d] =
        f2bf((d & 1) ? fmaf(kn, c, partner * sn) : fmaf(kn, c, -partner * sn));
  }
#pragma unroll
  for (int r = 0; r < 4; ++r) {  // q RoPE in-place, pre-scaled by 0.125
    int e = r * 256 + tid;
    int dq = e & 63;
    float cq = tr[dq >> 1], sq = tr[32 + (dq >> 1)];
    float qv = bf2f(row[e]);
    float partner = __shfl_xor(qv, 1);
    float qr = (e & 1) ? fmaf(qv, cq, partner * sq) : fmaf(qv, cq, -partner * sq);
    row[e] = f2bf(qr * 0.125f);
  }
}

// ---------------- vb [h][s][d] -> vtb [h][d][s] -----------------------------
#define TPAD 66
__global__ __launch_bounds__(256) void vtrans_k(const u16* __restrict__ vb,
                                               u16* __restrict__ vtb) {
  __shared__ u16 tile[64 * TPAD];
  int h = blockIdx.y, s0 = blockIdx.x * 64;
  int t = threadIdx.x;
  {
    int r = t >> 2, cb = (t & 3) * 16;
    const u16* src = vb + ((size_t)h * 2048 + s0 + r) * 64 + cb;
    *(uint4*)&tile[r * TPAD + cb] = *(const uint4*)src;
    *(uint4*)&tile[r * TPAD + cb + 8] = *(const uint4*)(src + 8);
  }
  __syncthreads();
  int d = t >> 2, sb = (t & 3) * 16;
  u16 vals[16];
#pragma unroll
  for (int j = 0; j < 16; ++j) vals[j] = tile[(sb + j) * TPAD + d];
  uint4 a, b;
  a.x = (u32)vals[0] | ((u32)vals[1] << 16);
  a.y = (u32)vals[2] | ((u32)vals[3] << 16);
  a.z = (u32)vals[4] | ((u32)vals[5] << 16);
  a.w = (u32)vals[6] | ((u32)vals[7] << 16);
  b.x = (u32)vals[8] | ((u32)vals[9] << 16);
  b.y = (u32)vals[10] | ((u32)vals[11] << 16);
  b.z = (u32)vals[12] | ((u32)vals[13] << 16);
  b.w = (u32)vals[14] | ((u32)vals[15] << 16);
  u16* dst = vtb + ((size_t)h * 64 + d) * 2048 + s0 + sb;
  *(uint4*)dst = a;
  *(uint4*)(dst + 8) = b;
}

// ---------------- MFMA causal attention, 8-wave parity, gll16 + LDS-P -------
// (round-17 version: best measured). Per-wave LDS P tile (in-order, no
// barrier), XOR-swizzled K/V staged via global_load_lds, fixed-50 softmax.
__global__ __launch_bounds__(512) void attn_k(
    const u16* __restrict__ qkvrb, const u16* __restrict__ kb,
    const u16* __restrict__ vtb, const float* __restrict__ g,
    u16* __restrict__ aob) {
  __shared__ __align__(16) u16 smem[40960];  // 80KB: 64KB K/V dbuf + 16KB Pw
  int head = blockIdx.x, hkv = head >> 2;
  int tid = threadIdx.x;
  int w = tid >> 6, l = tid & 63;
  int grp = w >> 2, wi = w & 3;
  int lr = l & 15, lg = l >> 4;
  int gtid = wi * 64 + l;
  u16* KsBase = smem + grp * 16384;  // buf b: Ks = +b*8192, Vt = Ks + 4096
  u32* pw = (u32*)(smem + 32768) + (size_t)w * 512;  // per-wave 16 x 32 u32
  float* mbuf = (float*)smem;        // merge: 256 x 17 f32 (17.4 KB, aliases)
  f32x4 zero = {0.f, 0.f, 0.f, 0.f};
  const float C1 = 0.057707801635558534f;  // 0.04 * log2(e)
  const float C2 = -144.26950408889634f;   // -100 * log2(e)
  int sw = (lr & 7) << 2;                  // P-tile column swizzle
  int u0 = ((lg ^ (lr & 7)) << 3);         // K/V physical u16 offset of unit
  int srow = l >> 3;
  int sunit = (l & 7) ^ srow;
  const u16* ksrc = kb + ((size_t)hkv * 2048 + srow) * 64 + sunit * 8;
  const u16* vsrc = vtb + ((size_t)(hkv * 64 + srow)) * 2048 + sunit * 8;
#pragma unroll 1
  for (int half = 0; half < 2; ++half) {
    int rb = half ? (int)blockIdx.y : (31 - (int)blockIdx.y);
    int row0 = rb * 64;
    const u16* qrow = qkvrb + (size_t)(row0 + wi * 16 + lr) * 1920 + head * 64;
    bf16x8 qf0 = *(const bf16x8*)&qrow[lg * 8];
    bf16x8 qf1 = *(const bf16x8*)&qrow[32 + lg * 8];
    f32x4 acc_o[4];
#pragma unroll
    for (int nd = 0; nd < 4; ++nd) acc_o[nd] = zero;
    float l_part = 0.f;
    int qglob = row0 + wi * 16 + lr;
    int c = grp;
    if (c <= rb) {  // prologue: stage chunk g into buf0 (async)
#pragma unroll
      for (int t = 0; t < 2; ++t) {
        int seg = wi * 2 + t;
        gll16(ksrc + (size_t)(c * 64 + seg * 8) * 64, KsBase + seg * 512);
        gll16(vsrc + (size_t)(seg * 8) * 2048 + c * 64,
              KsBase + 4096 + seg * 512);
      }
    }
    __syncthreads();  // drains vmcnt: buf0 ready
    int nmax = (rb >> 1) + 1;
#pragma unroll 1
    for (int i = 0; i < nmax; ++i, c += 2) {
      bool valid = (c <= rb);
      if (c + 2 <= rb) {  // async-stage chunk c+2 into other buf (overlaps)
        u16* Ksn = KsBase + ((i & 1) ^ 1) * 8192;
        int nc = c + 2;
#pragma unroll
        for (int t = 0; t < 2; ++t) {
          int seg = wi * 2 + t;
          gll16(ksrc + (size_t)(nc * 64 + seg * 8) * 64, Ksn + seg * 512);
          gll16(vsrc + (size_t)(seg * 8) * 2048 + nc * 64,
                Ksn + 4096 + seg * 512);
        }
      }
      if (valid) {
        u16* Ks = KsBase + (i & 1) * 8192;
        u16* Vt = Ks + 4096;
        int kbase = c * 64;
        __builtin_amdgcn_s_setprio(1);
        // swapped QK^T: A=K (row=key, k=d), B=q (col=q) -> D[key][q]
        f32x4 sa[4];
#pragma unroll
        for (int ni = 0; ni < 4; ++ni) {
          const u16* kp = &Ks[(ni * 16 + lr) * 64];
          bf16x8 a0 = *(const bf16x8*)&kp[u0];
          bf16x8 a1 = *(const bf16x8*)&kp[u0 ^ 32];
          f32x4 t = __builtin_amdgcn_mfma_f32_16x16x32_bf16(a0, qf0, zero, 0, 0, 0);
          sa[ni] = __builtin_amdgcn_mfma_f32_16x16x32_bf16(a1, qf1, t, 0, 0, 0);
        }
        bool diag = (c == rb);
        // p = exp(50*tanh(s/50)-50) = exp2(C2/(exp2(C1*s)+1)); row-sum scalar
        // write P (bf16-packed) into per-wave LDS tile, swizzled columns
#pragma unroll
        for (int ni = 0; ni < 4; ++ni) {
          float pv[4];
#pragma unroll
          for (int r = 0; r < 4; ++r) {
            float sv = sa[ni][r];
            float e = __builtin_amdgcn_exp2f(sv * C1);
            float p = __builtin_amdgcn_exp2f(C2 * __builtin_amdgcn_rcpf(e + 1.f));
            if (diag && (kbase + ni * 16 + lg * 4 + r) > qglob) p = 0.f;
            pv[r] = p;
            l_part += p;
          }
          u32 w0, w1;
          asm("v_cvt_pk_bf16_f32 %0, %1, %2" : "=v"(w0) : "v"(pv[0]), "v"(pv[1]));
          asm("v_cvt_pk_bf16_f32 %0, %1, %2" : "=v"(w1) : "v"(pv[2]), "v"(pv[3]));
          uint2 pr;
          pr.x = w0;
          pr.y = w1;
          *(uint2*)&pw[lr * 32 + ((ni * 8 + lg * 2) ^ sw)] = pr;
        }
        // read PV A-fragments back (wave-internal LDS: in-order, no barrier)
        bf16x8 pfa = *(const bf16x8*)&pw[lr * 32 + ((lg * 4) ^ sw)];
        bf16x8 pfb = *(const bf16x8*)&pw[lr * 32 + ((16 + lg * 4) ^ sw)];
        // PV: A=P (row=q, k=key), B=V^T (col=d, k=key)
#pragma unroll
        for (int nd = 0; nd < 4; ++nd) {
          const u16* vp = &Vt[(nd * 16 + lr) * 64];
          bf16x8 v0 = *(const bf16x8*)&vp[u0];
          bf16x8 v1 = *(const bf16x8*)&vp[u0 ^ 32];
          acc_o[nd] = __builtin_amdgcn_mfma_f32_16x16x32_bf16(pfa, v0, acc_o[nd], 0, 0, 0);
          acc_o[nd] = __builtin_amdgcn_mfma_f32_16x16x32_bf16(pfb, v1, acc_o[nd], 0, 0, 0);
        }
        __builtin_amdgcn_s_setprio(0);
      }
      __syncthreads();  // the only barrier per chunk (drains vmcnt+lgkm)
    }
    // reduce l within wave (sum 4 lg copies of each q-row)
    l_part += __shfl_xor(l_part, 16);
    l_part += __shfl_xor(l_part, 32);
    // merge groups via LDS (buffers dead after final loop barrier)
    if (grp == 1) {
      float* mb = mbuf + (size_t)gtid * 17;
#pragma unroll
      for (int nd = 0; nd < 4; ++nd)
#pragma unroll
        for (int r = 0; r < 4; ++r) mb[nd * 4 + r] = acc_o[nd][r];
      mb[16] = l_part;
    }
    __syncthreads();
    if (grp == 0) {
      const float* mb = mbuf + (size_t)gtid * 17;
      float lt = l_part + mb[16];
#pragma unroll
      for (int r = 0; r < 4; ++r) {
        int row = row0 + wi * 16 + lg * 4 + r;
        float lv = __shfl(lt, lg * 4 + r);
        float sc = g[row * 16 + head] * __builtin_amdgcn_rcpf(lv);
#pragma unroll
        for (int nd = 0; nd < 4; ++nd)
          aob[(size_t)row * 1024 + head * 64 + nd * 16 + lr] =
              f2bf((acc_o[nd][r] + mb[nd * 4 + r]) * sc);
      }
    }
    __syncthreads();  // mbuf reads done before next half restages buffers
  }
}

extern "C" void kernel_launch(void* const* d_in, const int* in_sizes, int n_in,
                              void* d_out, int out_size, void* d_ws,
                              size_t ws_size, hipStream_t stream) {
  const float* x = (const float*)d_in[0];
  const int* positions = (const int*)d_in[1];
  const float* Wq = (const float*)d_in[3];
  const float* Wk = (const float*)d_in[4];
  const float* Wv = (const float*)d_in[5];
  const float* Wo = (const float*)d_in[6];
  const float* Wg = (const float*)d_in[7];
  const float* Wm = (const float*)d_in[8];
  const float* bm = (const float*)d_in[9];
  const float* Wvr = (const float*)d_in[10];
  const float* ksc = (const float*)d_in[11];
  float* out = (float*)d_out;

  u16* xb = (u16*)d_ws;                            // 2048*1024
  u16* WallT = xb + (size_t)2048 * 1024;           // 1920*1024
  u16* WoT = WallT + (size_t)1920 * 1024;          // 1024*1024
  u16* qkvrb = WoT + (size_t)1024 * 1024;          // 2048*1920
  u16* kbuf = qkvrb + (size_t)2048 * 1920;         // 4*2048*64
  u16* vbuf = kbuf + (size_t)4 * 2048 * 64;
  u16* vtb = vbuf + (size_t)4 * 2048 * 64;
  float* gbuf = (float*)(vtb + (size_t)4 * 2048 * 64);  // 2048*16 f32
  float* rtab = gbuf + (size_t)2048 * 16;               // 2048*64 f32
  u16* aob = xb;  // xb dead after gemm1

  prep_all_k<<<4224, 256, 0, stream>>>(x, positions, Wq, Wk, Wv, Wvr, Wo, Wg,
                                       Wm, xb, WallT, WoT, rtab);
  gemm_bf16_k<128, true><<<dim3(15, 16), 512, 0, stream>>>(xb, WallT, qkvrb,
                                                           2048, 1920, 1024);
  postproc_k<<<2048, 256, 0, stream>>>(bm, ksc, rtab, qkvrb, kbuf, vbuf, gbuf);
  vtrans_k<<<dim3(32, 4), 256, 0, stream>>>(vbuf, vtb);
  attn_k<<<dim3(16, 16), 512, 0, stream>>>(qkvrb, kbuf, vtb, gbuf, aob);
  gemm_bf16_k<64, false><<<dim3(8, 32), 512, 0, stream>>>(aob, WoT, out, 2048,
                                                          1024, 1024);
}